// Round 3
// baseline (462.394 us; speedup 1.0000x reference)
//
#include <hip/hip_runtime.h>
#include <math.h>

#define HIDDEN 256
#define NEG 1024
#define NBATCH 256
#define GAMMA_F 12.0f
#define BM 32          // rows per tile
#define NTILES 8       // tiles per block
#define NBLK 1024      // grid

typedef short v8s __attribute__((ext_vector_type(8)));
typedef float v4f __attribute__((ext_vector_type(4)));

// fp32 -> bf16 round-to-nearest-even
__device__ __forceinline__ short f2bf(float x) {
    unsigned int u = __float_as_uint(x);
    u = (u + 0x7fffu + ((u >> 16) & 1u)) >> 16;
    return (short)u;
}

// One block per batch row b: h_n[b,:], rel_part[b,:] in fp32; convert W1 row b -> bf16.
__global__ __launch_bounds__(256) void prep_kernel(
    const int* __restrict__ head, const int* __restrict__ relation,
    const float* __restrict__ entity_emb, const float* __restrict__ relation_emb,
    const float* __restrict__ W_fc, const float* __restrict__ b_fc,
    short* __restrict__ W1bf, float* __restrict__ h_n, float* __restrict__ rel_part)
{
    const int b = blockIdx.x;
    const int t = threadIdx.x;

    W1bf[b * HIDDEN + t] = f2bf(W_fc[(size_t)b * 2 * HIDDEN + t]);

    __shared__ float xh[2 * HIDDEN];
    __shared__ float xt[HIDDEN];
    __shared__ float red[256];

    const int hidx = head[b];
    const int r = relation[b];
    xh[t]          = entity_emb[(size_t)hidx * HIDDEN + t];
    xh[HIDDEN + t] = relation_emb[(size_t)r * 2 * HIDDEN + t];
    xt[t]          = relation_emb[(size_t)r * 2 * HIDDEN + HIDDEN + t];
    __syncthreads();

    const float4* wrow = reinterpret_cast<const float4*>(W_fc + (size_t)t * 2 * HIDDEN);
    float hf = b_fc[t];
    float rp = b_fc[t];
    #pragma unroll 4
    for (int kk = 0; kk < HIDDEN / 4; ++kk) {
        float4 w = wrow[kk];
        hf += xh[4*kk+0]*w.x + xh[4*kk+1]*w.y + xh[4*kk+2]*w.z + xh[4*kk+3]*w.w;
    }
    #pragma unroll 4
    for (int kk = 0; kk < HIDDEN / 4; ++kk) {
        float4 w = wrow[HIDDEN/4 + kk];
        hf += xh[HIDDEN+4*kk+0]*w.x + xh[HIDDEN+4*kk+1]*w.y + xh[HIDDEN+4*kk+2]*w.z + xh[HIDDEN+4*kk+3]*w.w;
        rp += xt[4*kk+0]*w.x + xt[4*kk+1]*w.y + xt[4*kk+2]*w.z + xt[4*kk+3]*w.w;
    }
    rel_part[b * HIDDEN + t] = rp;

    red[t] = hf * hf;
    __syncthreads();
    for (int s = 128; s > 0; s >>= 1) {
        if (t < s) red[t] += red[t + s];
        __syncthreads();
    }
    const float norm = sqrtf(red[0]);
    h_n[b * HIDDEN + t] = hf / fmaxf(norm, 1e-12f);
}

// Persistent blocks: 8 tiles of 32 gathered rows each, double-buffered LDS.
// Gather for tile j+1 is issued (registers) before computing tile j, so the
// ~900-cyc HBM latency hides behind the K-loop + epilogue.
// LDS unit (16B) for (mt,kt,g,c): mt*512 + kt*64 + g*16 + c  (== t + 256*i).
__global__ __launch_bounds__(256, 4) void score_kernel(
    const int* __restrict__ tail, const float* __restrict__ entity_emb,
    const short* __restrict__ W1bf, const float* __restrict__ h_n,
    const float* __restrict__ rel_part, float* __restrict__ out)
{
    __shared__ __align__(16) short As[2][BM * HIDDEN];  // 2 x 16 KiB
    __shared__ int tails[NTILES * BM];                  // 1 KiB
    __shared__ float ssq_lds[4][BM];
    __shared__ float l1_lds[4][BM];

    const int t = threadIdx.x;
    const int w   = t >> 6;
    const int l   = t & 63;
    const int c   = t & 15;
    const int g   = (t >> 4) & 3;
    const int kt0 = t >> 6;              // 0..3
    const int base = blockIdx.x * NTILES;
    const int b    = blockIdx.x >> 2;    // all 8 tiles share batch row b

    tails[t] = tail[base * BM + t];      // all rows for this block's 8 tiles

    // hoisted epilogue constants (b fixed per block)
    float rlv[4], hnv[4];
    #pragma unroll
    for (int ntl = 0; ntl < 4; ++ntl) {
        const int n = 64 * w + ntl * 16 + c;
        rlv[ntl] = rel_part[b * HIDDEN + n];
        hnv[ntl] = h_n[b * HIDDEN + n];
    }

    __syncthreads();                     // tails visible

    // gather issue for tile j: 8 independent dwordx4 loads per thread
    auto issue = [&](int j, float4* ld) {
        const int r0 = tails[j * BM + c];
        const int r1 = tails[j * BM + 16 + c];
        const float* p0 = entity_emb + (size_t)r0 * HIDDEN + kt0 * 32 + g * 8;
        const float* p1 = entity_emb + (size_t)r1 * HIDDEN + kt0 * 32 + g * 8;
        ld[0] = reinterpret_cast<const float4*>(p0)[0];
        ld[1] = reinterpret_cast<const float4*>(p0)[1];
        ld[2] = reinterpret_cast<const float4*>(p0 + 128)[0];   // kt0+4
        ld[3] = reinterpret_cast<const float4*>(p0 + 128)[1];
        ld[4] = reinterpret_cast<const float4*>(p1)[0];
        ld[5] = reinterpret_cast<const float4*>(p1)[1];
        ld[6] = reinterpret_cast<const float4*>(p1 + 128)[0];
        ld[7] = reinterpret_cast<const float4*>(p1 + 128)[1];
    };

    float4 ld[8];
    issue(0, ld);

    #pragma unroll
    for (int j = 0; j < NTILES; ++j) {
        const int cur = j & 1;

        // convert + lane-linear LDS write (conflict-free) of tile j
        short* dst = As[cur] + t * 8;
        #pragma unroll
        for (int i = 0; i < 4; ++i) {
            float4 a0 = ld[2 * i], a1 = ld[2 * i + 1];
            v8s v;
            v[0]=f2bf(a0.x); v[1]=f2bf(a0.y); v[2]=f2bf(a0.z); v[3]=f2bf(a0.w);
            v[4]=f2bf(a1.x); v[5]=f2bf(a1.y); v[6]=f2bf(a1.z); v[7]=f2bf(a1.w);
            *reinterpret_cast<v8s*>(dst + i * 2048) = v;   // unit t + 256*i
        }

        // prefetch tile j+1 while tile j computes
        if (j < NTILES - 1) issue(j + 1, ld);

        __syncthreads();

        // K-loop: 16 ds_read_b128 + 64 MFMA per wave; B fragments from L2
        v4f acc[2][4];
        #pragma unroll
        for (int mt = 0; mt < 2; ++mt)
            #pragma unroll
            for (int ntl = 0; ntl < 4; ++ntl)
                acc[mt][ntl] = v4f{0.f, 0.f, 0.f, 0.f};

        #pragma unroll
        for (int kt = 0; kt < 8; ++kt) {
            v8s a0 = *reinterpret_cast<const v8s*>(As[cur] + (kt * 64 + l) * 8);
            v8s a1 = *reinterpret_cast<const v8s*>(As[cur] + (512 + kt * 64 + l) * 8);
            #pragma unroll
            for (int ntl = 0; ntl < 4; ++ntl) {
                v8s bf = *reinterpret_cast<const v8s*>(
                    W1bf + (size_t)(64 * w + ntl * 16 + c) * HIDDEN + kt * 32 + g * 8);
                acc[0][ntl] = __builtin_amdgcn_mfma_f32_16x16x32_bf16(a0, bf, acc[0][ntl], 0, 0, 0);
                acc[1][ntl] = __builtin_amdgcn_mfma_f32_16x16x32_bf16(a1, bf, acc[1][ntl], 0, 0, 0);
            }
        }

        // epilogue: row m = mt*16 + g*4 + r, col n = 64w + ntl*16 + c
        #pragma unroll
        for (int mt = 0; mt < 2; ++mt) {
            float ssq[4] = {0.f, 0.f, 0.f, 0.f};
            #pragma unroll
            for (int ntl = 0; ntl < 4; ++ntl) {
                #pragma unroll
                for (int r = 0; r < 4; ++r) {
                    float tf = acc[mt][ntl][r] + rlv[ntl];
                    acc[mt][ntl][r] = tf;
                    ssq[r] += tf * tf;
                }
            }
            #pragma unroll
            for (int mask = 1; mask < 16; mask <<= 1) {
                #pragma unroll
                for (int r = 0; r < 4; ++r) ssq[r] += __shfl_xor(ssq[r], mask);
            }
            if (c == 0) {
                #pragma unroll
                for (int r = 0; r < 4; ++r) ssq_lds[w][mt * 16 + g * 4 + r] = ssq[r];
            }
        }
        __syncthreads();

        #pragma unroll
        for (int mt = 0; mt < 2; ++mt) {
            float rn[4], s1[4] = {0.f, 0.f, 0.f, 0.f};
            #pragma unroll
            for (int r = 0; r < 4; ++r) {
                const int m = mt * 16 + g * 4 + r;
                float tot = ssq_lds[0][m] + ssq_lds[1][m] + ssq_lds[2][m] + ssq_lds[3][m];
                rn[r] = 1.f / fmaxf(sqrtf(tot), 1e-12f);
            }
            #pragma unroll
            for (int ntl = 0; ntl < 4; ++ntl) {
                #pragma unroll
                for (int r = 0; r < 4; ++r)
                    s1[r] += fabsf(hnv[ntl] - acc[mt][ntl][r] * rn[r]);
            }
            #pragma unroll
            for (int mask = 1; mask < 16; mask <<= 1) {
                #pragma unroll
                for (int r = 0; r < 4; ++r) s1[r] += __shfl_xor(s1[r], mask);
            }
            if (c == 0) {
                #pragma unroll
                for (int r = 0; r < 4; ++r) l1_lds[w][mt * 16 + g * 4 + r] = s1[r];
            }
        }
        __syncthreads();

        if (t < BM) {
            out[(base + j) * BM + t] = GAMMA_F -
                (l1_lds[0][t] + l1_lds[1][t] + l1_lds[2][t] + l1_lds[3][t]);
        }
        // next iteration's As[(j+1)&1] writes are safe: that buffer was last
        // read in iteration j-1, and every wave has passed this iteration's
        // barriers before any wave reaches those writes.
    }
}

extern "C" void kernel_launch(void* const* d_in, const int* in_sizes, int n_in,
                              void* d_out, int out_size, void* d_ws, size_t ws_size,
                              hipStream_t stream)
{
    const int*   head         = (const int*)d_in[0];
    const int*   tail         = (const int*)d_in[1];
    const int*   relation     = (const int*)d_in[2];
    const float* entity_emb   = (const float*)d_in[3];
    const float* relation_emb = (const float*)d_in[4];
    const float* W_fc         = (const float*)d_in[5];
    const float* b_fc         = (const float*)d_in[6];
    float* out = (float*)d_out;

    // ws layout: W1 bf16 (128 KiB) | h_n f32 (256 KiB) | rel_part f32 (256 KiB)
    short* W1bf     = (short*)d_ws;
    float* h_n      = (float*)((char*)d_ws + 131072);
    float* rel_part = (float*)((char*)d_ws + 131072 + 262144);

    prep_kernel<<<NBATCH, 256, 0, stream>>>(head, relation, entity_emb, relation_emb,
                                            W_fc, b_fc, W1bf, h_n, rel_part);
    score_kernel<<<NBLK, 256, 0, stream>>>(tail, entity_emb, W1bf,
                                           h_n, rel_part, out);
}

// Round 4
// 349.042 us; speedup vs baseline: 1.3248x; 1.3248x over previous
//
#include <hip/hip_runtime.h>
#include <math.h>

#define HIDDEN 256
#define NEG 1024
#define NBATCH 256
#define GAMMA_F 12.0f
#define BM 32          // rows per tile
#define NTILES 8       // tiles per block
#define NBLK 1024      // (NBATCH*NEG)/(BM*NTILES)

typedef short v8s __attribute__((ext_vector_type(8)));
typedef float v4f __attribute__((ext_vector_type(4)));
typedef unsigned int u32;

// raw barrier: wait LDS ops only, do NOT drain vmcnt (keeps DMA prefetch in flight)
#define LDS_BARRIER() asm volatile("s_waitcnt lgkmcnt(0)\n\ts_barrier" ::: "memory")

// fp32 -> bf16 round-to-nearest-even (scalar, prep kernel)
__device__ __forceinline__ short f2bf(float x) {
    u32 u = __float_as_uint(x);
    u = (u + 0x7fffu + ((u >> 16) & 1u)) >> 16;
    return (short)u;
}

// pack 8 fp32 -> v8s bf16 (round-half-up + v_perm byte-pack, 12 VALU)
__device__ __forceinline__ u32 rhu(float f) { return __float_as_uint(f) + 0x8000u; }
__device__ __forceinline__ v8s pack8(const float4& x0, const float4& x1) {
    int4 fr;
    fr.x = __builtin_amdgcn_perm(rhu(x0.y), rhu(x0.x), 0x07060302u);
    fr.y = __builtin_amdgcn_perm(rhu(x0.w), rhu(x0.z), 0x07060302u);
    fr.z = __builtin_amdgcn_perm(rhu(x1.y), rhu(x1.x), 0x07060302u);
    fr.w = __builtin_amdgcn_perm(rhu(x1.w), rhu(x1.z), 0x07060302u);
    return __builtin_bit_cast(v8s, fr);
}

// One block per batch row b: h_n[b,:], rel_part[b,:] in fp32; convert W1 row b -> bf16.
__global__ __launch_bounds__(256) void prep_kernel(
    const int* __restrict__ head, const int* __restrict__ relation,
    const float* __restrict__ entity_emb, const float* __restrict__ relation_emb,
    const float* __restrict__ W_fc, const float* __restrict__ b_fc,
    short* __restrict__ W1bf, float* __restrict__ h_n, float* __restrict__ rel_part)
{
    const int b = blockIdx.x;
    const int t = threadIdx.x;

    W1bf[b * HIDDEN + t] = f2bf(W_fc[(size_t)b * 2 * HIDDEN + t]);

    __shared__ float xh[2 * HIDDEN];
    __shared__ float xt[HIDDEN];
    __shared__ float red[256];

    const int hidx = head[b];
    const int r = relation[b];
    xh[t]          = entity_emb[(size_t)hidx * HIDDEN + t];
    xh[HIDDEN + t] = relation_emb[(size_t)r * 2 * HIDDEN + t];
    xt[t]          = relation_emb[(size_t)r * 2 * HIDDEN + HIDDEN + t];
    __syncthreads();

    const float4* wrow = reinterpret_cast<const float4*>(W_fc + (size_t)t * 2 * HIDDEN);
    float hf = b_fc[t];
    float rp = b_fc[t];
    #pragma unroll 4
    for (int kk = 0; kk < HIDDEN / 4; ++kk) {
        float4 w = wrow[kk];
        hf += xh[4*kk+0]*w.x + xh[4*kk+1]*w.y + xh[4*kk+2]*w.z + xh[4*kk+3]*w.w;
    }
    #pragma unroll 4
    for (int kk = 0; kk < HIDDEN / 4; ++kk) {
        float4 w = wrow[HIDDEN/4 + kk];
        hf += xh[HIDDEN+4*kk+0]*w.x + xh[HIDDEN+4*kk+1]*w.y + xh[HIDDEN+4*kk+2]*w.z + xh[HIDDEN+4*kk+3]*w.w;
        rp += xt[4*kk+0]*w.x + xt[4*kk+1]*w.y + xt[4*kk+2]*w.z + xt[4*kk+3]*w.w;
    }
    rel_part[b * HIDDEN + t] = rp;

    red[t] = hf * hf;
    __syncthreads();
    for (int s = 128; s > 0; s >>= 1) {
        if (t < s) red[t] += red[t + s];
        __syncthreads();
    }
    const float norm = sqrtf(red[0]);
    h_n[b * HIDDEN + t] = hf / fmaxf(norm, 1e-12f);
}

// Persistent-ish blocks: NTILES tiles of BM=32 gathered rows, double-buffered
// fp32 LDS filled by global_load_lds DMA (no staging VGPRs -> no spill).
// LDS row layout: row r occupies 64 contiguous 16B units; global unit u of
// row r lands at LDS unit r*64 + (u ^ (r&7)) (XOR swizzle applied on the DMA
// SOURCE address), giving exactly 8 lanes/quad-bank on every ds_read_b128.
// B fragments (this wave's 64 cols x full K) are preloaded into 128 VGPRs:
// the K-loop is VMEM-free, so only DMA occupies vmcnt and raw
// s_waitcnt vmcnt(8) barriers keep the j+1 prefetch in flight while tile j
// computes. LDS = 67.6 KB caps occupancy at 2 blocks/CU so the allocator
// targets 256 VGPRs and keeps Bf resident (R3 post-mortem lesson).
__global__ __launch_bounds__(256, 2) void score_kernel(
    const int* __restrict__ tail, const float* __restrict__ entity_emb,
    const short* __restrict__ W1bf, const float* __restrict__ h_n,
    const float* __restrict__ rel_part, float* __restrict__ out)
{
    __shared__ __align__(16) float Asf[2][BM * HIDDEN];  // 2 x 32 KiB
    __shared__ int tails[NTILES * BM];                   // 1 KiB
    __shared__ float ssq_lds[4][BM];
    __shared__ float l1_lds[4][BM];

    const int t = threadIdx.x;
    const int w = t >> 6;
    const int l = t & 63;
    const int c = t & 15;
    const int g = (t >> 4) & 3;
    const int b = blockIdx.x >> 2;       // 4 blocks per batch row

    tails[t] = tail[blockIdx.x * (NTILES * BM) + t];

    // hoisted epilogue constants
    float rlv[4], hnv[4];
    #pragma unroll
    for (int ntl = 0; ntl < 4; ++ntl) {
        const int n = 64 * w + ntl * 16 + c;
        rlv[ntl] = rel_part[b * HIDDEN + n];
        hnv[ntl] = h_n[b * HIDDEN + n];
    }

    // preload this wave's B fragments: cols 64w..64w+63, full K (128 VGPRs)
    v8s Bf[4][8];
    #pragma unroll
    for (int ntl = 0; ntl < 4; ++ntl) {
        const short* bsrc = W1bf + (size_t)(64 * w + ntl * 16 + c) * HIDDEN + g * 8;
        #pragma unroll
        for (int kt = 0; kt < 8; ++kt)
            Bf[ntl][kt] = *reinterpret_cast<const v8s*>(bsrc + kt * 32);
    }

    __syncthreads();   // tails visible (no DMA outstanding yet, drain harmless)

    // DMA one tile: 8 calls/wave, call i = local row r = w*8+i (1 KiB, coalesced)
    auto issue = [&](int j, int buf) {
        #pragma unroll
        for (int i = 0; i < 8; ++i) {
            const int r = w * 8 + i;
            const int row = tails[j * BM + r];
            const float* src = entity_emb + (size_t)row * HIDDEN + ((l ^ (r & 7)) << 2);
            __builtin_amdgcn_global_load_lds(
                (const __attribute__((address_space(1))) u32*)src,
                (__attribute__((address_space(3))) u32*)&Asf[buf][r * HIDDEN],
                16, 0, 0);
        }
    };

    issue(0, 0);

    #pragma unroll 1
    for (int j = 0; j < NTILES; ++j) {
        const int cur = j & 1;

        if (j + 1 < NTILES) {
            issue(j + 1, cur ^ 1);                       // prefetch stays in flight
            asm volatile("s_waitcnt vmcnt(8)" ::: "memory");  // tile j's DMA done
        } else {
            asm volatile("s_waitcnt vmcnt(0)" ::: "memory");
        }
        asm volatile("s_barrier" ::: "memory");

        v4f acc[2][4];
        #pragma unroll
        for (int mt = 0; mt < 2; ++mt)
            #pragma unroll
            for (int ntl = 0; ntl < 4; ++ntl)
                acc[mt][ntl] = v4f{0.f, 0.f, 0.f, 0.f};

        const float* a0base = &Asf[cur][c * HIDDEN];          // mt=0, row c
        const float* a1base = &Asf[cur][(16 + c) * HIDDEN];   // mt=1, row 16+c
        const int swz = c & 7;

        #pragma unroll
        for (int kt = 0; kt < 8; ++kt) {
            const int u0 = kt * 8 + g * 2;
            float4 x0 = *reinterpret_cast<const float4*>(a0base + (((u0    ) ^ swz) << 2));
            float4 x1 = *reinterpret_cast<const float4*>(a0base + (((u0 + 1) ^ swz) << 2));
            float4 y0 = *reinterpret_cast<const float4*>(a1base + (((u0    ) ^ swz) << 2));
            float4 y1 = *reinterpret_cast<const float4*>(a1base + (((u0 + 1) ^ swz) << 2));
            v8s a0 = pack8(x0, x1);
            v8s a1 = pack8(y0, y1);
            #pragma unroll
            for (int ntl = 0; ntl < 4; ++ntl) {
                acc[0][ntl] = __builtin_amdgcn_mfma_f32_16x16x32_bf16(a0, Bf[ntl][kt], acc[0][ntl], 0, 0, 0);
                acc[1][ntl] = __builtin_amdgcn_mfma_f32_16x16x32_bf16(a1, Bf[ntl][kt], acc[1][ntl], 0, 0, 0);
            }
        }

        // epilogue: row m = mt*16 + g*4 + r, col n = 64w + ntl*16 + c
        #pragma unroll
        for (int mt = 0; mt < 2; ++mt) {
            float ssq[4] = {0.f, 0.f, 0.f, 0.f};
            #pragma unroll
            for (int ntl = 0; ntl < 4; ++ntl) {
                #pragma unroll
                for (int r = 0; r < 4; ++r) {
                    float tf = acc[mt][ntl][r] + rlv[ntl];
                    acc[mt][ntl][r] = tf;
                    ssq[r] += tf * tf;
                }
            }
            #pragma unroll
            for (int mask = 1; mask < 16; mask <<= 1) {
                #pragma unroll
                for (int r = 0; r < 4; ++r) ssq[r] += __shfl_xor(ssq[r], mask);
            }
            if (c == 0) {
                #pragma unroll
                for (int r = 0; r < 4; ++r) ssq_lds[w][mt * 16 + g * 4 + r] = ssq[r];
            }
        }
        LDS_BARRIER();

        #pragma unroll
        for (int mt = 0; mt < 2; ++mt) {
            float rn[4], s1[4] = {0.f, 0.f, 0.f, 0.f};
            #pragma unroll
            for (int r = 0; r < 4; ++r) {
                const int m = mt * 16 + g * 4 + r;
                float tot = ssq_lds[0][m] + ssq_lds[1][m] + ssq_lds[2][m] + ssq_lds[3][m];
                rn[r] = 1.f / fmaxf(sqrtf(tot), 1e-12f);
            }
            #pragma unroll
            for (int ntl = 0; ntl < 4; ++ntl) {
                #pragma unroll
                for (int r = 0; r < 4; ++r)
                    s1[r] += fabsf(hnv[ntl] - acc[mt][ntl][r] * rn[r]);
            }
            #pragma unroll
            for (int mask = 1; mask < 16; mask <<= 1) {
                #pragma unroll
                for (int r = 0; r < 4; ++r) s1[r] += __shfl_xor(s1[r], mask);
            }
            if (c == 0) {
                #pragma unroll
                for (int r = 0; r < 4; ++r) l1_lds[w][mt * 16 + g * 4 + r] = s1[r];
            }
        }
        LDS_BARRIER();

        if (t < BM) {
            out[blockIdx.x * (NTILES * BM) + j * BM + t] = GAMMA_F -
                (l1_lds[0][t] + l1_lds[1][t] + l1_lds[2][t] + l1_lds[3][t]);
        }
        // buffer safety: DMA for tile j+2 (into buf cur) is issued in iter j+1,
        // strictly after this iteration's last barrier, which is after all
        // waves' K-loop reads of buf cur completed (lgkmcnt(0) at barrier 1).
    }
}

extern "C" void kernel_launch(void* const* d_in, const int* in_sizes, int n_in,
                              void* d_out, int out_size, void* d_ws, size_t ws_size,
                              hipStream_t stream)
{
    const int*   head         = (const int*)d_in[0];
    const int*   tail         = (const int*)d_in[1];
    const int*   relation     = (const int*)d_in[2];
    const float* entity_emb   = (const float*)d_in[3];
    const float* relation_emb = (const float*)d_in[4];
    const float* W_fc         = (const float*)d_in[5];
    const float* b_fc         = (const float*)d_in[6];
    float* out = (float*)d_out;

    // ws layout: W1 bf16 (128 KiB) | h_n f32 (256 KiB) | rel_part f32 (256 KiB)
    short* W1bf     = (short*)d_ws;
    float* h_n      = (float*)((char*)d_ws + 131072);
    float* rel_part = (float*)((char*)d_ws + 131072 + 262144);

    prep_kernel<<<NBATCH, 256, 0, stream>>>(head, relation, entity_emb, relation_emb,
                                            W_fc, b_fc, W1bf, h_n, rel_part);
    score_kernel<<<NBLK, 256, 0, stream>>>(tail, entity_emb, W1bf,
                                           h_n, rel_part, out);
}